// Round 16
// baseline (2030.939 us; speedup 1.0000x reference)
//
#include <hip/hip_runtime.h>

// Fused flash-style softmax(Q V^T) V, B=4, NQ=NK=4096, D=1024, fp32 in/out.
// Round 16: BQ=16 (grid 1024 blocks). Halves per-wave accumulator/Q state
// (oacc 32, qf 16, sacc 8 regs) so total regs fit 128/wave -> 4 waves/SIMD
// -> TWO independent co-resident blocks per CU (r13/r14 proved the runtime
// co-schedules when regs allow). LDS ~18 KB/block (2 blocks = 36 KB).
// Structure otherwise r15 (fp16 V prepass: V16 for QK^T staging, VT16 for
// PV B-frags; spart cross-wave reduction; defer-max softmax; lane-local l).
// Duplicate softmax groups (32 groups for 16 q) compute identical values and
// write identical bytes - benign. Arithmetic per q unchanged vs r15.

#define NB   4
#define NQL  4096
#define NKL  4096
#define DIM  1024
#define BQ   16
#define BK   32
#define NW   8
#define DSL  128
#define NT   (NKL / BK)
#define LOG2E 1.44269504088896340736f
#define PBW  40            // pbuf row stride in shorts (80 B)

typedef float f32x2 __attribute__((ext_vector_type(2)));
typedef float f32x4 __attribute__((ext_vector_type(4)));
typedef _Float16 f16x8 __attribute__((ext_vector_type(8)));
typedef short s16x8 __attribute__((ext_vector_type(8)));
typedef short s16x4 __attribute__((ext_vector_type(4)));
typedef unsigned int uint_;

union Frag { f16x8 v; s16x8 s; _Float16 h[8]; };

__device__ __forceinline__ void rawbar() {  // LDS visibility only
    asm volatile("s_waitcnt lgkmcnt(0)\n\ts_barrier" ::: "memory");
}

// ---------------- Prepass: V fp32 -> V16 (same layout) + VT16 (transposed) ----
__global__ void prep_v(const float* __restrict__ Vg, short* __restrict__ v16,
                       short* __restrict__ vt16) {
    __shared__ short lds[64][72];   // +8 pad
    const int t   = (int)threadIdx.x;
    const int blk = (int)blockIdx.x;
    const int bb    = blk >> 10;
    const int ktile = (blk >> 4) & 63;
    const int dtile = blk & 15;
    const int k0 = ktile * 64, d0 = dtile * 64;
    const int row = t >> 2;            // 0..63
    const int cb  = (t & 3) * 16;      // 0,16,32,48

    const float* src = Vg + ((size_t)(bb * NKL + k0 + row) * DIM + d0 + cb);
    short* vdst = v16 + ((size_t)(bb * NKL + k0 + row) * DIM + d0 + cb);
#pragma unroll
    for (int i = 0; i < 4; ++i) {
        f32x4 x = *(const f32x4*)(src + i * 4);
        s16x4 h;
#pragma unroll
        for (int j = 0; j < 4; ++j)
            h[j] = __builtin_bit_cast(short, (_Float16)x[j]);
        *(s16x4*)(vdst + i * 4) = h;
        *(s16x4*)&lds[row][cb + i * 4] = h;
    }
    __syncthreads();
    short* tdst = vt16 + ((size_t)(bb * DIM + d0 + row) * NKL + k0 + cb);
#pragma unroll
    for (int i = 0; i < 4; ++i) {
        s16x4 h;
#pragma unroll
        for (int j = 0; j < 4; ++j)
            h[j] = lds[cb + i * 4 + j][row];
        *(s16x4*)(tdst + i * 4) = h;
    }
}

// ---------------- Main kernel (MODE 1 = fp16 prepass; MODE 0 = fp32 direct) --
template<int MODE>
__global__ __attribute__((amdgpu_flat_work_group_size(512, 512),
                          amdgpu_waves_per_eu(2, 8)))
void attn_f16(const float* __restrict__ Qg, const float* __restrict__ Vg,
              float* __restrict__ Og, const short* __restrict__ v16,
              const short* __restrict__ vt16) {
    __shared__ float spart[NW][BQ][BK];                   // 16 KB (swizzled k idx)
    __shared__ __align__(16) short pbuf[BQ * PBW];        // 1.25 KB (fp16 P)
    __shared__ float arun[BQ];
    __shared__ float lsum[BQ];

    const int tid = (int)threadIdx.x;
    const int l   = tid & 63;
    const int w   = tid >> 6;
    const int l15 = l & 15;
    const int lg  = l >> 4;

    // XCD-aware swizzle (1024 blocks, 8 XCDs, bijective since 1024%8==0)
    const int bid  = (int)blockIdx.x;
    const int orig = (bid & 7) * 128 + (bid >> 3);
    const int b  = orig >> 8;          // 256 q-tiles per batch
    const int qt = orig & 255;
    const int q0 = qt * BQ;
    const int dw = w * DSL;

    // Q fragments (B-operand): lane holds Q[q0+l15][dw+dc*32+lg*8 .. +7] fp16
    f16x8 qf[4];
#pragma unroll
    for (int dc = 0; dc < 4; ++dc) {
        const float* qp = Qg + (size_t)(b * NQL + q0 + l15) * DIM
                        + dw + dc * 32 + lg * 8;
        f32x4 x0 = *(const f32x4*)qp;
        f32x4 x1 = *(const f32x4*)(qp + 4);
        f16x8 a;
#pragma unroll
        for (int j = 0; j < 4; ++j) { a[j] = (_Float16)x0[j]; a[j + 4] = (_Float16)x1[j]; }
        qf[dc] = a;
    }

    f32x4 oacc[8];
#pragma unroll
    for (int dg = 0; dg < 8; ++dg)
        oacc[dg] = (f32x4){0.f, 0.f, 0.f, 0.f};

    f32x4 sacc[2];
    f32x4 hA32[4][2], hB32[4][2];   // MODE 0 staging
    s16x8 hA16[4], hB16[4];         // MODE 1 staging

    auto loadhalf = [&](int buf, int kt_, int kb) {
        if constexpr (MODE == 1) {
            const short* vp = v16 + ((size_t)(b * NKL + kt_ * BK + kb * 16 + l15) * DIM
                            + dw + lg * 8);
            s16x8 (&hb)[4] = buf ? hB16 : hA16;
#pragma unroll
            for (int dc = 0; dc < 4; ++dc)
                hb[dc] = *(const s16x8*)(vp + dc * 32);
        } else {
            const float* vp = Vg + (size_t)(b * NKL + kt_ * BK + kb * 16 + l15) * DIM
                            + dw + lg * 8;
            f32x4 (&hb)[4][2] = buf ? hB32 : hA32;
#pragma unroll
            for (int dc = 0; dc < 4; ++dc) {
                hb[dc][0] = *(const f32x4*)(vp + dc * 32);
                hb[dc][1] = *(const f32x4*)(vp + dc * 32 + 4);
            }
        }
    };

    auto computehalf = [&](int buf, int kb) {
#pragma unroll
        for (int dc = 0; dc < 4; ++dc) {
            Frag fa;
            if constexpr (MODE == 1) {
                fa.s = buf ? hB16[dc] : hA16[dc];
            } else {
                f32x4 (&hb)[4][2] = buf ? hB32 : hA32;
#pragma unroll
                for (int j = 0; j < 4; ++j) {
                    fa.h[j]     = (_Float16)hb[dc][0][j];
                    fa.h[j + 4] = (_Float16)hb[dc][1][j];
                }
            }
            sacc[kb] = __builtin_amdgcn_mfma_f32_16x16x32_f16(fa.v, qf[dc], sacc[kb], 0, 0, 0);
        }
    };

    // softmax: group g=4w+lg handles q=(g&15); groups 16..31 duplicate (benign)
    const int qsm = (4 * w + lg) & 15;
    const int kk  = (2 * l15) ^ ((qsm & 7) << 2);

    float m_reg  = -3e38f;
    float l_lane = 0.f;

    loadhalf(0, 0, 0);
    loadhalf(1, 0, 1);
    rawbar();

    for (int kt = 0; kt < NT; ++kt) {
        sacc[0] = (f32x4){0.f, 0.f, 0.f, 0.f};
        sacc[1] = (f32x4){0.f, 0.f, 0.f, 0.f};

        const int ktn = (kt + 1 < NT) ? kt + 1 : NT - 1;
        computehalf(0, 0);
        loadhalf(0, ktn, 0);
        computehalf(1, 1);
        loadhalf(1, ktn, 1);

        // S^T partials -> spart (b128 stores, XOR-swizzled k-block)
#pragma unroll
        for (int kb = 0; kb < 2; ++kb) {
            const int q = l15;
            const int kblk = (kb * 16 + lg * 4) ^ ((q & 7) << 2);
            *(f32x4*)&spart[w][q][kblk] = sacc[kb];
        }
        rawbar();  // B1

        // MODE 0 only: PV fp32 dword gather
        float pv[8][8];
        if constexpr (MODE == 0) {
            const float* vb = Vg + (size_t)(b * NKL + kt * BK + lg * 8) * DIM
                            + dw + l15;
#pragma unroll
            for (int dg = 0; dg < 8; ++dg)
#pragma unroll
                for (int j = 0; j < 8; ++j)
                    pv[dg][j] = vb[(size_t)j * DIM + dg * 16];
        }

        // Phase 2: reduce over waves, defer-max online softmax
        {
            f32x2 sp = (f32x2){0.f, 0.f};
#pragma unroll
            for (int wv = 0; wv < NW; ++wv)
                sp += *(const f32x2*)&spart[wv][qsm][kk];
            float s0 = sp[0], s1 = sp[1];
            float smax = fmaxf(s0, s1);
            float alpha = 1.0f;
            if (!__all(smax - m_reg <= 8.0f)) {
                float mloc = smax;
#pragma unroll
                for (int off = 1; off < 16; off <<= 1)
                    mloc = fmaxf(mloc, __shfl_xor(mloc, off));
                float mnew = fmaxf(m_reg, mloc);
                alpha = exp2f((m_reg - mnew) * LOG2E);
                m_reg = mnew;
            }
            float p0 = exp2f((s0 - m_reg) * LOG2E);
            float p1 = exp2f((s1 - m_reg) * LOG2E);
            l_lane = alpha * l_lane + (p0 + p1);
            if (l15 == 0) arun[qsm] = alpha;
            uint_ pk = (uint_)__builtin_bit_cast(unsigned short, (_Float16)p0)
                     | ((uint_)__builtin_bit_cast(unsigned short, (_Float16)p1) << 16);
            *(uint_*)&pbuf[qsm * PBW + 2 * l15] = pk;
        }
        rawbar();  // B2

        // Phase 3: conditional rescale, then O += P * V
        {
            f32x4 av = *(const f32x4*)&arun[lg * 4];
            bool mine1 = (av[0] == 1.0f) && (av[1] == 1.0f)
                      && (av[2] == 1.0f) && (av[3] == 1.0f);
            if (!__all(mine1)) {
#pragma unroll
                for (int dg = 0; dg < 8; ++dg)
#pragma unroll
                    for (int r = 0; r < 4; ++r)
                        oacc[dg][r] *= av[r];
            }
        }

        Frag pf;
        pf.s = *(const s16x8*)&pbuf[l15 * PBW + lg * 8];

        const short* vtb = (MODE == 1)
            ? vt16 + ((size_t)(b * DIM + dw + l15) * NKL + kt * BK + lg * 8)
            : nullptr;

#pragma unroll
        for (int dg = 0; dg < 8; ++dg) {
            Frag bf;
            if constexpr (MODE == 1) {
                bf.s = *(const s16x8*)(vtb + (size_t)dg * 16 * NKL);
            } else {
#pragma unroll
                for (int j = 0; j < 8; ++j)
                    bf.h[j] = (_Float16)pv[dg][j];
            }
            __builtin_amdgcn_s_setprio(1);
            oacc[dg] = __builtin_amdgcn_mfma_f32_16x16x32_f16(
                pf.v, bf.v, oacc[dg], 0, 0, 0);
            __builtin_amdgcn_s_setprio(0);
        }
    }

    // Epilogue: reduce l across the 16-lane group, normalize, store.
    {
        float rs = l_lane;
#pragma unroll
        for (int off = 1; off < 16; off <<= 1)
            rs += __shfl_xor(rs, off);
        if (l15 == 0) lsum[qsm] = rs;
    }
    __syncthreads();
    {
        f32x4 lv = *(const f32x4*)&lsum[lg * 4];
        float il[4];
#pragma unroll
        for (int r = 0; r < 4; ++r) il[r] = 1.0f / lv[r];
#pragma unroll
        for (int dg = 0; dg < 8; ++dg)
#pragma unroll
            for (int r = 0; r < 4; ++r) {
                int q = q0 + lg * 4 + r;
                int d = dw + dg * 16 + l15;
                Og[(size_t)(b * NQL + q) * DIM + d] = oacc[dg][r] * il[r];
            }
    }
}

extern "C" void kernel_launch(void* const* d_in, const int* in_sizes, int n_in,
                              void* d_out, int out_size, void* d_ws, size_t ws_size,
                              hipStream_t stream) {
    const float* Q = (const float*)d_in[0];
    const float* V = (const float*)d_in[1];
    float* O = (float*)d_out;
    (void)in_sizes; (void)n_in; (void)out_size;

    const size_t elems = (size_t)NB * NKL * DIM;          // 16.78M
    const size_t need  = 2 * elems * sizeof(short);       // 64 MB
    dim3 grid(NB * (NQL / BQ));  // 1024 blocks
    dim3 block(NW * 64);         // 512 threads
    if (ws_size >= need) {
        short* v16  = (short*)d_ws;
        short* vt16 = v16 + elems;
        prep_v<<<dim3(NB * 1024), dim3(256), 0, stream>>>(V, v16, vt16);
        attn_f16<1><<<grid, block, 0, stream>>>(Q, V, O, v16, vt16);
    } else {
        attn_f16<0><<<grid, block, 0, stream>>>(Q, V, O, nullptr, nullptr);
    }
}

// Round 17
// 935.768 us; speedup vs baseline: 2.1703x; 2.1703x over previous
//
#include <hip/hip_runtime.h>

// Fused flash-style softmax(Q V^T) V, B=4, NQ=NK=4096, D=1024, fp32 in/out.
// Round 17: r15 (BQ=32, fp16 V prepass) restructured into a 1-barrier-per-
// tile software pipeline with double-buffered spart/pbuf/arun:
//   region A_i: QK^T(i) -> spart[i&1]  ||  vt16 loads(i-1)  ||  softmax(i-1)
//   barrier_i
//   region B_i: PV(i-1)           (flows into A_{i+1} with no barrier)
// Phase latencies now overlap inside region A instead of being serialized by
// a second barrier. Arithmetic order per q is unchanged vs r15.

#define NB   4
#define NQL  4096
#define NKL  4096
#define DIM  1024
#define BQ   32
#define BK   32
#define NW   8
#define DSL  128
#define NT   (NKL / BK)
#define LOG2E 1.44269504088896340736f
#define PBW  40            // pbuf row stride in shorts (80 B)

typedef float f32x2 __attribute__((ext_vector_type(2)));
typedef float f32x4 __attribute__((ext_vector_type(4)));
typedef _Float16 f16x8 __attribute__((ext_vector_type(8)));
typedef short s16x8 __attribute__((ext_vector_type(8)));
typedef short s16x4 __attribute__((ext_vector_type(4)));
typedef unsigned int uint_;

union Frag { f16x8 v; s16x8 s; _Float16 h[8]; };

__device__ __forceinline__ void rawbar() {  // LDS visibility only
    asm volatile("s_waitcnt lgkmcnt(0)\n\ts_barrier" ::: "memory");
}

// ---------------- Prepass: V fp32 -> V16 (same layout) + VT16 (transposed) ----
__global__ void prep_v(const float* __restrict__ Vg, short* __restrict__ v16,
                       short* __restrict__ vt16) {
    __shared__ short lds[64][72];
    const int t   = (int)threadIdx.x;
    const int blk = (int)blockIdx.x;
    const int bb    = blk >> 10;
    const int ktile = (blk >> 4) & 63;
    const int dtile = blk & 15;
    const int k0 = ktile * 64, d0 = dtile * 64;
    const int row = t >> 2;
    const int cb  = (t & 3) * 16;

    const float* src = Vg + ((size_t)(bb * NKL + k0 + row) * DIM + d0 + cb);
    short* vdst = v16 + ((size_t)(bb * NKL + k0 + row) * DIM + d0 + cb);
#pragma unroll
    for (int i = 0; i < 4; ++i) {
        f32x4 x = *(const f32x4*)(src + i * 4);
        s16x4 h;
#pragma unroll
        for (int j = 0; j < 4; ++j)
            h[j] = __builtin_bit_cast(short, (_Float16)x[j]);
        *(s16x4*)(vdst + i * 4) = h;
        *(s16x4*)&lds[row][cb + i * 4] = h;
    }
    __syncthreads();
    short* tdst = vt16 + ((size_t)(bb * DIM + d0 + row) * NKL + k0 + cb);
#pragma unroll
    for (int i = 0; i < 4; ++i) {
        s16x4 h;
#pragma unroll
        for (int j = 0; j < 4; ++j)
            h[j] = lds[cb + i * 4 + j][row];
        *(s16x4*)(tdst + i * 4) = h;
    }
}

// ---------------- Main kernel (MODE 1 = fp16 prepass; MODE 0 = fp32 direct) --
template<int MODE>
__global__ __attribute__((amdgpu_flat_work_group_size(512, 512),
                          amdgpu_waves_per_eu(2, 4)))
void attn_f16(const float* __restrict__ Qg, const float* __restrict__ Vg,
              float* __restrict__ Og, const short* __restrict__ v16,
              const short* __restrict__ vt16) {
    __shared__ float spart[2][NW][BQ][BK];                // 64 KB, double-buffered
    __shared__ __align__(16) short pbuf[2][BQ * PBW];     // 5 KB
    __shared__ float arun[2][BQ];
    __shared__ float lsum[BQ];

    const int tid = (int)threadIdx.x;
    const int l   = tid & 63;
    const int w   = tid >> 6;
    const int l15 = l & 15;
    const int lg  = l >> 4;

    // XCD-aware swizzle (512 blocks, 8 XCDs, bijective)
    const int bid  = (int)blockIdx.x;
    const int orig = (bid & 7) * 64 + (bid >> 3);
    const int b  = orig >> 7;
    const int qt = orig & 127;
    const int q0 = qt * BQ;
    const int dw = w * DSL;

    // Q fragments (B-operand), fp32->fp16 once per block
    f16x8 qf[2][4];
#pragma unroll
    for (int qb = 0; qb < 2; ++qb)
#pragma unroll
        for (int dc = 0; dc < 4; ++dc) {
            const float* qp = Qg + (size_t)(b * NQL + q0 + qb * 16 + l15) * DIM
                            + dw + dc * 32 + lg * 8;
            f32x4 x0 = *(const f32x4*)qp;
            f32x4 x1 = *(const f32x4*)(qp + 4);
            f16x8 a;
#pragma unroll
            for (int j = 0; j < 4; ++j) { a[j] = (_Float16)x0[j]; a[j + 4] = (_Float16)x1[j]; }
            qf[qb][dc] = a;
        }

    f32x4 oacc[2][8];
#pragma unroll
    for (int qb = 0; qb < 2; ++qb)
#pragma unroll
        for (int dg = 0; dg < 8; ++dg)
            oacc[qb][dg] = (f32x4){0.f, 0.f, 0.f, 0.f};

    f32x4 sacc[2][2];
    f32x4 hA32[4][2], hB32[4][2];   // MODE 0 staging
    s16x8 hA16[4], hB16[4];         // MODE 1 staging

    auto loadstage = [&](int buf, int kt_, int kb) {
        if constexpr (MODE == 1) {
            const short* vp = v16 + ((size_t)(b * NKL + kt_ * BK + kb * 16 + l15) * DIM
                            + dw + lg * 8);
            s16x8 (&hb)[4] = buf ? hB16 : hA16;
#pragma unroll
            for (int dc = 0; dc < 4; ++dc)
                hb[dc] = *(const s16x8*)(vp + dc * 32);
        } else {
            const float* vp = Vg + (size_t)(b * NKL + kt_ * BK + kb * 16 + l15) * DIM
                            + dw + lg * 8;
            f32x4 (&hb)[4][2] = buf ? hB32 : hA32;
#pragma unroll
            for (int dc = 0; dc < 4; ++dc) {
                hb[dc][0] = *(const f32x4*)(vp + dc * 32);
                hb[dc][1] = *(const f32x4*)(vp + dc * 32 + 4);
            }
        }
    };

    auto qkt_half = [&](int buf, int kb) {
#pragma unroll
        for (int dc = 0; dc < 4; ++dc) {
            Frag fa;
            if constexpr (MODE == 1) {
                fa.s = buf ? hB16[dc] : hA16[dc];
            } else {
                f32x4 (&hb)[4][2] = buf ? hB32 : hA32;
#pragma unroll
                for (int j = 0; j < 4; ++j) {
                    fa.h[j]     = (_Float16)hb[dc][0][j];
                    fa.h[j + 4] = (_Float16)hb[dc][1][j];
                }
            }
            sacc[kb][0] = __builtin_amdgcn_mfma_f32_16x16x32_f16(fa.v, qf[0][dc], sacc[kb][0], 0, 0, 0);
            sacc[kb][1] = __builtin_amdgcn_mfma_f32_16x16x32_f16(fa.v, qf[1][dc], sacc[kb][1], 0, 0, 0);
        }
    };

    auto qkt_tile = [&](int kt_, int spbuf) {
#pragma unroll
        for (int kb = 0; kb < 2; ++kb)
#pragma unroll
            for (int qb = 0; qb < 2; ++qb)
                sacc[kb][qb] = (f32x4){0.f, 0.f, 0.f, 0.f};
        const int ktn = (kt_ + 1 < NT) ? kt_ + 1 : NT - 1;
        qkt_half(0, 0);
        loadstage(0, ktn, 0);
        qkt_half(1, 1);
        loadstage(1, ktn, 1);
#pragma unroll
        for (int kb = 0; kb < 2; ++kb)
#pragma unroll
            for (int qb = 0; qb < 2; ++qb) {
                const int q = qb * 16 + l15;
                const int kblk = (kb * 16 + lg * 4) ^ ((q & 7) << 2);
                *(f32x4*)&spart[spbuf][w][q][kblk] = sacc[kb][qb];
            }
    };

    // softmax assignment: lane handles q = 4w+lg, k-pair {2*l15, 2*l15+1}
    const int qsm = 4 * w + lg;
    const int kk  = (2 * l15) ^ ((qsm & 7) << 2);

    float m_reg  = -3e38f;
    float l_lane = 0.f;

    auto softmax_tile = [&](int cur) {
        f32x2 sp = (f32x2){0.f, 0.f};
#pragma unroll
        for (int wv = 0; wv < NW; ++wv)
            sp += *(const f32x2*)&spart[cur][wv][qsm][kk];
        float s0 = sp[0], s1 = sp[1];
        float smax = fmaxf(s0, s1);
        float alpha = 1.0f;
        if (!__all(smax - m_reg <= 8.0f)) {
            float mloc = smax;
#pragma unroll
            for (int off = 1; off < 16; off <<= 1)
                mloc = fmaxf(mloc, __shfl_xor(mloc, off));
            float mnew = fmaxf(m_reg, mloc);
            alpha = exp2f((m_reg - mnew) * LOG2E);
            m_reg = mnew;
        }
        float p0 = exp2f((s0 - m_reg) * LOG2E);
        float p1 = exp2f((s1 - m_reg) * LOG2E);
        l_lane = alpha * l_lane + (p0 + p1);
        if (l15 == 0) arun[cur][qsm] = alpha;
        uint_ pk = (uint_)__builtin_bit_cast(unsigned short, (_Float16)p0)
                 | ((uint_)__builtin_bit_cast(unsigned short, (_Float16)p1) << 16);
        *(uint_*)&pbuf[cur][qsm * PBW + 2 * l15] = pk;
    };

    s16x8 pvreg[8];                 // MODE 1: vt16 frags preloaded in region A
    float pv32[8][8];               // MODE 0: fp32 gather (region B)

    auto pv_loads = [&](int kt_) {
        if constexpr (MODE == 1) {
            const short* vtb = vt16 + ((size_t)(b * DIM + dw + l15) * NKL
                             + kt_ * BK + lg * 8);
#pragma unroll
            for (int dg = 0; dg < 8; ++dg)
                pvreg[dg] = *(const s16x8*)(vtb + (size_t)dg * 16 * NKL);
        }
    };

    auto pv_tile = [&](int kt_, int cur) {
        if constexpr (MODE == 0) {
            const float* vb = Vg + (size_t)(b * NKL + kt_ * BK + lg * 8) * DIM
                            + dw + l15;
#pragma unroll
            for (int dg = 0; dg < 8; ++dg)
#pragma unroll
                for (int j = 0; j < 8; ++j)
                    pv32[dg][j] = vb[(size_t)j * DIM + dg * 16];
        }
        f32x4 av[2];
#pragma unroll
        for (int qb = 0; qb < 2; ++qb)
            av[qb] = *(const f32x4*)&arun[cur][qb * 16 + lg * 4];
        bool mine1 = true;
#pragma unroll
        for (int qb = 0; qb < 2; ++qb)
#pragma unroll
            for (int r = 0; r < 4; ++r)
                mine1 = mine1 && (av[qb][r] == 1.0f);
        if (!__all(mine1)) {
#pragma unroll
            for (int qb = 0; qb < 2; ++qb)
#pragma unroll
                for (int dg = 0; dg < 8; ++dg)
#pragma unroll
                    for (int r = 0; r < 4; ++r)
                        oacc[qb][dg][r] *= av[qb][r];
        }
        Frag pf[2];
#pragma unroll
        for (int qb = 0; qb < 2; ++qb)
            pf[qb].s = *(const s16x8*)&pbuf[cur][(qb * 16 + l15) * PBW + lg * 8];
#pragma unroll
        for (int dg = 0; dg < 8; ++dg) {
            Frag bf;
            if constexpr (MODE == 1) {
                bf.s = pvreg[dg];
            } else {
#pragma unroll
                for (int j = 0; j < 8; ++j)
                    bf.h[j] = (_Float16)pv32[dg][j];
            }
            __builtin_amdgcn_s_setprio(1);
#pragma unroll
            for (int qb = 0; qb < 2; ++qb)
                oacc[qb][dg] = __builtin_amdgcn_mfma_f32_16x16x32_f16(
                    pf[qb].v, bf.v, oacc[qb][dg], 0, 0, 0);
            __builtin_amdgcn_s_setprio(0);
        }
    };

    // ---- Prologue: stage tile 0, QK^T(0) -> spart[0], barrier
    loadstage(0, 0, 0);
    loadstage(1, 0, 1);
    qkt_tile(0, 0);
    rawbar();

    // ---- Pipelined main loop: one barrier per tile
    for (int kt = 1; kt < NT; ++kt) {
        const int cur = (kt - 1) & 1;
        // region A: QK^T(kt) -> spart[kt&1] || PV loads(kt-1) || softmax(kt-1)
        pv_loads(kt - 1);
        qkt_tile(kt, kt & 1);
        softmax_tile(cur);
        rawbar();
        // region B: PV(kt-1); flows into next region A without a barrier
        pv_tile(kt - 1, cur);
    }

    // ---- Tail: softmax + PV for tile NT-1
    {
        const int cur = (NT - 1) & 1;
        pv_loads(NT - 1);
        softmax_tile(cur);
        rawbar();
        pv_tile(NT - 1, cur);
    }

    // ---- Epilogue: reduce l across the 16-lane group, normalize, store
    {
        float rs = l_lane;
#pragma unroll
        for (int off = 1; off < 16; off <<= 1)
            rs += __shfl_xor(rs, off);
        if (l15 == 0) lsum[qsm] = rs;
    }
    __syncthreads();
#pragma unroll
    for (int qb = 0; qb < 2; ++qb) {
        f32x4 lv = *(const f32x4*)&lsum[qb * 16 + lg * 4];
        float il[4];
#pragma unroll
        for (int r = 0; r < 4; ++r) il[r] = 1.0f / lv[r];
#pragma unroll
        for (int dg = 0; dg < 8; ++dg)
#pragma unroll
            for (int r = 0; r < 4; ++r) {
                int q = q0 + qb * 16 + lg * 4 + r;
                int d = dw + dg * 16 + l15;
                Og[(size_t)(b * NQL + q) * DIM + d] = oacc[qb][dg][r] * il[r];
            }
    }
}

extern "C" void kernel_launch(void* const* d_in, const int* in_sizes, int n_in,
                              void* d_out, int out_size, void* d_ws, size_t ws_size,
                              hipStream_t stream) {
    const float* Q = (const float*)d_in[0];
    const float* V = (const float*)d_in[1];
    float* O = (float*)d_out;
    (void)in_sizes; (void)n_in; (void)out_size;

    const size_t elems = (size_t)NB * NKL * DIM;          // 16.78M
    const size_t need  = 2 * elems * sizeof(short);       // 64 MB
    dim3 grid(NB * (NQL / BQ));  // 512 blocks
    dim3 block(NW * 64);         // 512 threads
    if (ws_size >= need) {
        short* v16  = (short*)d_ws;
        short* vt16 = v16 + elems;
        prep_v<<<dim3(NB * 1024), dim3(256), 0, stream>>>(V, v16, vt16);
        attn_f16<1><<<grid, block, 0, stream>>>(Q, V, O, v16, vt16);
    } else {
        attn_f16<0><<<grid, block, 0, stream>>>(Q, V, O, nullptr, nullptr);
    }
}